// Round 5
// baseline (663.182 us; speedup 1.0000x reference)
//
#include <hip/hip_runtime.h>

// ---------------------------------------------------------------------------
// VectorQuantizerEMA — round 5: occupancy-focused argmin (36 KB LDS, 4 blk/CU),
// coalesced convert, atomic weight accumulation (no sort machinery)
// ---------------------------------------------------------------------------

#define DECAY 0.99f
#define OMD   0.01f
#define EPSC  1e-5f
#define MARGIN 0.008f

constexpr int Dq = 256;
constexpr int Kn = 2048;
constexpr int Nq = 32768;

typedef short bf16x8 __attribute__((ext_vector_type(8)));
typedef float f32x4 __attribute__((ext_vector_type(4)));

__device__ __forceinline__ unsigned short f2bf_rne(float f) {
    unsigned int u = __float_as_uint(f);
    unsigned int r = u + 0x7FFFu + ((u >> 16) & 1u);
    return (unsigned short)(r >> 16);
}
__device__ __forceinline__ float bf2f(unsigned short h) {
    return __uint_as_float(((unsigned int)h) << 16);
}
__device__ __forceinline__ void async_copy16(const void* g, void* l) {
    __builtin_amdgcn_global_load_lds(
        (const __attribute__((address_space(1))) unsigned int*)g,
        (__attribute__((address_space(3))) unsigned int*)l, 16, 0, 0);
}
__device__ __forceinline__ uint4 packbf(const unsigned short* h) {
    uint4 u;
    u.x = (unsigned)h[0] | ((unsigned)h[1] << 16);
    u.y = (unsigned)h[2] | ((unsigned)h[3] << 16);
    u.z = (unsigned)h[4] | ((unsigned)h[5] << 16);
    u.w = (unsigned)h[6] | ((unsigned)h[7] << 16);
    return u;
}

// ---------------- convert: fp32 -> frag-order bf16 hi/lo planes + enorm -----
// One wave per 16-row block; each wave writes whole contiguous 1KB granule
// blocks (64 lanes x 16B covering [0,1024) disjointly) -> fully coalesced.
__global__ __launch_bounds__(256) void convert_kernel(
    const float* __restrict__ x, const float* __restrict__ emb,
    unsigned char* __restrict__ xh_g, unsigned char* __restrict__ xl_g,
    unsigned char* __restrict__ eh_g, unsigned char* __restrict__ el_g,
    float* __restrict__ enorm, int* __restrict__ counts,
    float* __restrict__ loss_acc, int* __restrict__ nflag)
{
    int t = threadIdx.x;
    if (blockIdx.x == 0) {
        for (int i = t; i < Kn; i += 256) counts[i] = 0;
        if (t == 0) { loss_acc[0] = 0.f; nflag[0] = 0; }
    }
    int wave = t >> 6, lane = t & 63;
    int g = blockIdx.x * 4 + wave;            // row-block (16 rows), 0..2175
    int r0 = g * 16;
    bool is_e = (r0 >= Nq);
    int gg = is_e ? (g - Nq / 16) : g;
    unsigned char* hg = is_e ? eh_g : xh_g;
    unsigned char* lg = is_e ? el_g : xl_g;
    int rl = lane >> 2, qd = lane & 3;
    int row = r0 + rl * 1 - (is_e ? Nq : 0) + 0;
    row = (r0 - (is_e ? Nq : 0)) + rl;
    const float* rp = (is_e ? emb : x) + (size_t)row * Dq;
    float esum = 0.f;
#pragma unroll
    for (int ds = 0; ds < 8; ++ds) {
        float4 v0 = *(const float4*)(rp + ds * 32 + qd * 8);
        float4 v1 = *(const float4*)(rp + ds * 32 + qd * 8 + 4);
        float vv[8] = {v0.x, v0.y, v0.z, v0.w, v1.x, v1.y, v1.z, v1.w};
        unsigned short hh[8], ll[8];
#pragma unroll
        for (int i = 0; i < 8; ++i) {
            hh[i] = f2bf_rne(vv[i]);
            ll[i] = f2bf_rne(vv[i] - bf2f(hh[i]));
        }
        size_t gb = ((size_t)gg * 8 + ds) * 1024 + qd * 256 + rl * 16;
        *(uint4*)(hg + gb) = packbf(hh);
        *(uint4*)(lg + gb) = packbf(ll);
        if (is_e) {
#pragma unroll
            for (int i = 0; i < 8; ++i) esum += vv[i] * vv[i];
        }
    }
    if (is_e) {
        esum += __shfl_xor(esum, 1, 64);
        esum += __shfl_xor(esum, 2, 64);
        if (qd == 0) enorm[row] = esum;
    }
}

// ---------------- argmin: MFMA 3-term, 36 KB LDS, 4 blocks/CU ---------------
// grid 512: qb = bx>>1 (128 q), split = bx&1 (1024 codes).
// 4 waves: wq=wave>>1 (q half), wk=wave&1 (k half). Chunk = 32 d (one K-step).
__global__ __launch_bounds__(256, 4) void argmin_kernel(
    const unsigned char* __restrict__ xh_g, const unsigned char* __restrict__ xl_g,
    const unsigned char* __restrict__ eh_g, const unsigned char* __restrict__ el_g,
    const float* __restrict__ enorm,
    float* __restrict__ ws_s1, float* __restrict__ ws_s2, int* __restrict__ ws_k)
{
    __shared__ __align__(16) unsigned char lds[36864]; // 4 planes x 8KB + 4KB enorm
    const int tid = threadIdx.x;
    const int lane = tid & 63, wave = tid >> 6;
    const int wq = wave >> 1, wk = wave & 1;
    const int rl = lane & 15, quad = lane >> 4;
    const int qb = blockIdx.x >> 1;
    const int split = blockIdx.x & 1;

    ((float4*)(lds + 32768))[tid] = ((const float4*)(enorm + split * 1024))[tid];

    float s1[16], s2[16];
    int i1[16];
#pragma unroll
    for (int s = 0; s < 16; ++s) { s1[s] = 3.4e38f; s2[s] = 3.4e38f; i1[s] = 0; }

    const unsigned char* pg = (wave == 0) ? xh_g : (wave == 1) ? xl_g
                              : (wave == 2) ? eh_g : el_g;
    const int rb_x = qb * 8;

    for (int kt = 0; kt < 8; ++kt) {
        f32x4 acc[4][4];
#pragma unroll
        for (int mf = 0; mf < 4; ++mf)
#pragma unroll
            for (int nf = 0; nf < 4; ++nf) acc[mf][nf] = (f32x4){0.f, 0.f, 0.f, 0.f};

        const int rbase = (wave < 2) ? rb_x : (split * 64 + kt * 8);

        for (int ch = 0; ch < 8; ++ch) {
            __syncthreads();
#pragma unroll
            for (int mfb = 0; mfb < 8; ++mfb) {
                size_t goff = ((size_t)(rbase + mfb) * 8 + ch) * 1024
                              + (size_t)lane * 16;
                async_copy16(pg + goff, lds + wave * 8192 + mfb * 1024);
            }
            __syncthreads();
            // B-frags (8) once, then per-mf A-frags (2) -> low VGPR pressure
            bf16x8 bh[4], bl[4];
#pragma unroll
            for (int nf = 0; nf < 4; ++nf) {
                int blk = (wk * 4 + nf) * 1024 + lane * 16;
                bh[nf] = *(const bf16x8*)(lds + 16384 + blk);
                bl[nf] = *(const bf16x8*)(lds + 24576 + blk);
            }
#pragma unroll
            for (int mf = 0; mf < 4; ++mf) {
                int blk = (wq * 4 + mf) * 1024 + lane * 16;
                bf16x8 ah = *(const bf16x8*)(lds + blk);
                bf16x8 al = *(const bf16x8*)(lds + 8192 + blk);
#pragma unroll
                for (int nf = 0; nf < 4; ++nf) {
                    acc[mf][nf] = __builtin_amdgcn_mfma_f32_16x16x32_bf16(
                        ah, bh[nf], acc[mf][nf], 0, 0, 0);
                    acc[mf][nf] = __builtin_amdgcn_mfma_f32_16x16x32_bf16(
                        ah, bl[nf], acc[mf][nf], 0, 0, 0);
                    acc[mf][nf] = __builtin_amdgcn_mfma_f32_16x16x32_bf16(
                        al, bh[nf], acc[mf][nf], 0, 0, 0);
                }
            }
        }
        // fold: score = enorm - 2*dot
#pragma unroll
        for (int nf = 0; nf < 4; ++nf) {
            float ee = *(const float*)(lds + 32768 +
                         (kt * 128 + wk * 64 + nf * 16 + rl) * 4);
            int code = kt * 4 + nf;
#pragma unroll
            for (int mf = 0; mf < 4; ++mf)
#pragma unroll
                for (int r = 0; r < 4; ++r) {
                    int slot = mf * 4 + r;
                    float sc = fmaf(-2.f, acc[mf][nf][r], ee);
                    float worst = fmaxf(s1[slot], sc);
                    s2[slot] = fminf(s2[slot], worst);
                    bool lt = sc < s1[slot];
                    s1[slot] = lt ? sc : s1[slot];
                    i1[slot] = lt ? code : i1[slot];
                }
        }
    }

    int kf[16];
#pragma unroll
    for (int s = 0; s < 16; ++s)
        kf[s] = split * 1024 + (i1[s] >> 2) * 128 + wk * 64 + (i1[s] & 3) * 16 + rl;
#pragma unroll
    for (int m = 1; m <= 8; m <<= 1) {
#pragma unroll
        for (int s = 0; s < 16; ++s) {
            float os1 = __shfl_xor(s1[s], m, 64);
            float os2 = __shfl_xor(s2[s], m, 64);
            int   ok  = __shfl_xor(kf[s], m, 64);
            float worst = fmaxf(s1[s], os1);
            s2[s] = fminf(fminf(s2[s], os2), worst);
            bool take = (os1 < s1[s]) || (os1 == s1[s] && ok < kf[s]);
            s1[s] = take ? os1 : s1[s];
            kf[s] = take ? ok : kf[s];
        }
    }
    __syncthreads();
    float* rs1 = (float*)lds;
    float* rs2 = (float*)(lds + 1024);
    int*   rk  = (int*)(lds + 2048);
    if (rl == 0) {
#pragma unroll
        for (int s = 0; s < 16; ++s) {
            int ql = wq * 64 + (s >> 2) * 16 + quad * 4 + (s & 3);
            rs1[ql * 2 + wk] = s1[s];
            rs2[ql * 2 + wk] = s2[s];
            rk[ql * 2 + wk]  = kf[s];
        }
    }
    __syncthreads();
    if (tid < 128) {
        float a1 = rs1[tid * 2], b1 = rs1[tid * 2 + 1];
        float a2 = rs2[tid * 2], b2 = rs2[tid * 2 + 1];
        int ka = rk[tid * 2], kb = rk[tid * 2 + 1];
        bool take = (b1 < a1) || (b1 == a1 && kb < ka);
        float fs1 = take ? b1 : a1;
        int   fk  = take ? kb : ka;
        float fs2 = fminf(fminf(a2, b2), fmaxf(a1, b1));
        int q = qb * 128 + tid;
        ws_s1[split * Nq + q] = fs1;
        ws_s2[split * Nq + q] = fs2;
        ws_k[split * Nq + q]  = fk;
    }
}

// ---------------- pick: merge splits, flag ambiguous, LDS histogram ---------
__global__ __launch_bounds__(256) void pick_kernel(
    const float* __restrict__ ws_s1, const float* __restrict__ ws_s2,
    const int* __restrict__ ws_k, int* __restrict__ idx,
    int* __restrict__ nflag, int* __restrict__ flaglist,
    int* __restrict__ counts)
{
    __shared__ int h[Kn];
    int t = threadIdx.x;
#pragma unroll
    for (int i = 0; i < 8; ++i) h[t + i * 256] = 0;
    __syncthreads();
    int q = blockIdx.x * 256 + t;
    float a1 = ws_s1[q], b1 = ws_s1[Nq + q];
    float a2 = ws_s2[q], b2 = ws_s2[Nq + q];
    int ka = ws_k[q], kb = ws_k[Nq + q];
    bool take = (b1 < a1) || (b1 == a1 && kb < ka);
    float s1 = take ? b1 : a1;
    int k = take ? kb : ka;
    float s2 = fminf(fminf(a2, b2), fmaxf(a1, b1));
    idx[q] = k;
    atomicAdd(&h[k], 1);
    if (s2 - s1 < MARGIN) {
        int p = atomicAdd(nflag, 1);
        flaglist[p] = q;
    }
    __syncthreads();
#pragma unroll
    for (int i = 0; i < 8; ++i) {
        int c = h[t + i * 256];
        if (c) atomicAdd(&counts[t + i * 256], c);
    }
}

// ---------------- rescue: exact fp32 argmin for flagged queries -------------
__global__ __launch_bounds__(256) void rescue_kernel(
    const float* __restrict__ x, const float* __restrict__ emb,
    const float* __restrict__ enorm, const int* __restrict__ flaglist,
    const int* __restrict__ nflag, int* __restrict__ idx,
    int* __restrict__ counts)
{
    __shared__ float xs[256];
    __shared__ float bsc[256];
    __shared__ int bix[256];
    int nf = nflag[0];
    int t = threadIdx.x;
    for (int it = blockIdx.x; it < nf; it += gridDim.x) {
        __syncthreads();
        int q = flaglist[it];
        xs[t] = x[(size_t)q * Dq + t];
        __syncthreads();
        float best = 3.4e38f;
        int bk = 0;
        for (int j = 0; j < 8; ++j) {
            int k = j * 256 + t;
            const float4* e4 = (const float4*)(emb + (size_t)k * Dq);
            const float4* x4 = (const float4*)xs;
            float d = 0.f;
#pragma unroll 8
            for (int c = 0; c < 64; ++c) {
                float4 e = e4[c], xv = x4[c];
                d = fmaf(e.x, xv.x, d); d = fmaf(e.y, xv.y, d);
                d = fmaf(e.z, xv.z, d); d = fmaf(e.w, xv.w, d);
            }
            float sc = enorm[k] - 2.f * d;
            if (sc < best || (sc == best && k < bk)) { best = sc; bk = k; }
        }
        bsc[t] = best; bix[t] = bk;
        __syncthreads();
        for (int o = 128; o > 0; o >>= 1) {
            if (t < o) {
                float so = bsc[t + o]; int io = bix[t + o];
                if (so < bsc[t] || (so == bsc[t] && io < bix[t])) {
                    bsc[t] = so; bix[t] = io;
                }
            }
            __syncthreads();
        }
        if (t == 0) {
            int newk = bix[0], oldk = idx[q];
            if (newk != oldk) {
                idx[q] = newk;
                atomicSub(&counts[oldk], 1);
                atomicAdd(&counts[newk], 1);
            }
        }
    }
}

// ---------------- scan: smoothed counts -------------------------------------
__global__ __launch_bounds__(256) void scan_kernel(
    const int* __restrict__ counts, const float* __restrict__ ema_count,
    float* __restrict__ cnew, float* __restrict__ out_count)
{
    __shared__ int   si[256];
    __shared__ float sf[256];
    int t = threadIdx.x;
    int c[8];
    int run = 0;
    float se = 0.f;
#pragma unroll
    for (int i = 0; i < 8; ++i) {
        c[i] = counts[t * 8 + i];
        run += c[i];
        se += ema_count[t * 8 + i];
    }
    si[t] = run;
    sf[t] = se;
    __syncthreads();
    for (int off = 128; off > 0; off >>= 1) {
        if (t < off) { si[t] += si[t + off]; sf[t] += sf[t + off]; }
        __syncthreads();
    }
    float total = DECAY * sf[0] + OMD * (float)si[0];
    float denom = total + 2048.0f * EPSC;
#pragma unroll
    for (int i = 0; i < 8; ++i) {
        int k = t * 8 + i;
        float ck = DECAY * ema_count[k] + OMD * (float)c[i];
        float v = (ck + EPSC) / denom * total;
        cnew[k] = v;
        out_count[k] = v;
    }
}

// ---------------- weight_direct: row-wise atomic accumulation ---------------
__global__ __launch_bounds__(256) void weight_direct_kernel(
    const float* __restrict__ x, const int* __restrict__ idx,
    float* __restrict__ accum)
{
    int n = blockIdx.x * 4 + (threadIdx.x >> 6);
    int lane = threadIdx.x & 63;
    int k = idx[n];
    float4 v = *(const float4*)(x + (size_t)n * Dq + lane * 4);
    float* a = accum + (size_t)k * Dq + lane * 4;
    atomicAdd(a + 0, v.x);
    atomicAdd(a + 1, v.y);
    atomicAdd(a + 2, v.z);
    atomicAdd(a + 3, v.w);
}

// ---------------- weight_final: EMA + divide --------------------------------
__global__ __launch_bounds__(256) void weight_final_kernel(
    const float* __restrict__ accum, const float* __restrict__ ema_weight,
    const float* __restrict__ cnew,
    float* __restrict__ out_embed, float* __restrict__ out_weight)
{
    int gi = blockIdx.x * 256 + threadIdx.x;   // float4 index
    int k = gi >> 6;
    float4 a = ((const float4*)accum)[gi];
    float4 ew = ((const float4*)ema_weight)[gi];
    float inv = 1.f / cnew[k];
    float4 w;
    w.x = DECAY * ew.x + OMD * a.x;
    w.y = DECAY * ew.y + OMD * a.y;
    w.z = DECAY * ew.z + OMD * a.z;
    w.w = DECAY * ew.w + OMD * a.w;
    ((float4*)out_weight)[gi] = w;
    float4 e;
    e.x = w.x * inv; e.y = w.y * inv; e.z = w.z * inv; e.w = w.w * inv;
    ((float4*)out_embed)[gi] = e;
}

// ---------------- finalize: idx_f + gather z_q + loss -----------------------
__global__ __launch_bounds__(256) void finalize_kernel(
    const int* __restrict__ idx, const float* __restrict__ x,
    const float* __restrict__ emb, float* __restrict__ idx_f_out,
    float* __restrict__ zq_out, float* __restrict__ loss_acc)
{
    __shared__ int sidx[64];
    __shared__ float lpart[4];
    const int tid = threadIdx.x;
    const int q0 = blockIdx.x * 64;
    if (tid < 64) {
        int b = idx[q0 + tid];
        idx_f_out[q0 + tid] = (float)b;
        sidx[tid] = b;
    }
    __syncthreads();
    int gq = tid >> 2, part = tid & 3;
    int bk = sidx[gq];
    const float4* ev = (const float4*)&emb[(size_t)bk * Dq + part * 64];
    const float4* xv = (const float4*)&x[(size_t)(q0 + gq) * Dq + part * 64];
    float4* ov = (float4*)&zq_out[(size_t)(q0 + gq) * Dq + part * 64];
    float lacc = 0.f;
#pragma unroll 4
    for (int t2 = 0; t2 < 16; ++t2) {
        float4 e4 = ev[t2];
        float4 x4 = xv[t2];
        ov[t2] = e4;
        float d0 = x4.x - e4.x, d1 = x4.y - e4.y;
        float d2 = x4.z - e4.z, d3 = x4.w - e4.w;
        lacc += d0 * d0 + d1 * d1 + d2 * d2 + d3 * d3;
    }
#pragma unroll
    for (int o = 32; o > 0; o >>= 1) lacc += __shfl_down(lacc, o, 64);
    if ((tid & 63) == 0) lpart[tid >> 6] = lacc;
    __syncthreads();
    if (tid == 0)
        atomicAdd(loss_acc, lpart[0] + lpart[1] + lpart[2] + lpart[3]);
}

// ---------------- loss_final ------------------------------------------------
__global__ void loss_final_kernel(const float* __restrict__ loss_acc,
                                  float* __restrict__ out_cb,
                                  float* __restrict__ out_cm) {
    float v = loss_acc[0] / (float)((size_t)Nq * Dq);
    out_cb[0] = v;
    out_cm[0] = v;
}

// ---------------------------------------------------------------------------
extern "C" void kernel_launch(void* const* d_in, const int* in_sizes, int n_in,
                              void* d_out, int out_size, void* d_ws, size_t ws_size,
                              hipStream_t stream) {
    const float* z_e        = (const float*)d_in[0];
    const float* emb        = (const float*)d_in[1];
    const float* ema_count  = (const float*)d_in[2];
    const float* ema_weight = (const float*)d_in[3];

    float* out_zq     = (float*)d_out;
    float* out_idx    = out_zq + (size_t)Nq * Dq;            // elt 8388608
    float* out_cb     = out_idx + Nq;
    float* out_cm     = out_cb + 1;
    float* out_embed  = out_cm + 1;                           // elt 8421378
    float* out_count  = out_embed + (size_t)Kn * Dq;
    float* out_weight = out_count + Kn;

    // scratch planes + accum live in d_out regions written later:
    unsigned char* xh_g = (unsigned char*)d_out;              // 16 MB (z_q area)
    unsigned char* xl_g = xh_g + 16777216;                    // 16 MB
    size_t eh_off = (((size_t)8421378 * 4) + 15) & ~(size_t)15;
    unsigned char* eh_g = (unsigned char*)d_out + eh_off;     // 1 MB (embed area)
    unsigned char* el_g = eh_g + 1048576;                     // 1 MB
    float* accum = (float*)d_out;                             // 2 MB, zeroed post-argmin

    char* ws = (char*)d_ws;
    float* enorm    = (float*)(ws + 0);
    int*   counts   = (int*)(ws + 8192);
    float* cnew     = (float*)(ws + 16384);
    float* loss_acc = (float*)(ws + 24576);
    int*   nflag    = (int*)(ws + 24580);
    int*   idx      = (int*)(ws + 32768);       // 32768 i
    int*   flaglist = (int*)(ws + 163840);      // 32768 i
    float* ws_s1    = (float*)(ws + 294912);    // 2*32768 f
    float* ws_s2    = (float*)(ws + 557056);    // 2*32768 f
    int*   ws_k     = (int*)(ws + 819200);      // 2*32768 i

    convert_kernel<<<544, 256, 0, stream>>>(z_e, emb, xh_g, xl_g, eh_g, el_g,
                                            enorm, counts, loss_acc, nflag);
    argmin_kernel<<<512, 256, 0, stream>>>(xh_g, xl_g, eh_g, el_g, enorm,
                                           ws_s1, ws_s2, ws_k);
    hipMemsetAsync(accum, 0, (size_t)Kn * Dq * sizeof(float), stream);
    pick_kernel<<<Nq / 256, 256, 0, stream>>>(ws_s1, ws_s2, ws_k, idx,
                                              nflag, flaglist, counts);
    rescue_kernel<<<128, 256, 0, stream>>>(z_e, emb, enorm, flaglist, nflag,
                                           idx, counts);
    scan_kernel<<<1, 256, 0, stream>>>(counts, ema_count, cnew, out_count);
    weight_direct_kernel<<<Nq / 4, 256, 0, stream>>>(z_e, idx, accum);
    weight_final_kernel<<<Kn * Dq / 1024, 256, 0, stream>>>(accum, ema_weight, cnew,
                                                            out_embed, out_weight);
    finalize_kernel<<<Nq / 64, 256, 0, stream>>>(idx, z_e, emb, out_idx,
                                                 out_zq, loss_acc);
    loss_final_kernel<<<1, 1, 0, stream>>>(loss_acc, out_cb, out_cm);
}

// Round 6
// 464.655 us; speedup vs baseline: 1.4273x; 1.4273x over previous
//
#include <hip/hip_runtime.h>

// ---------------------------------------------------------------------------
// VectorQuantizerEMA — round 6: round-4 argmin + XCD swizzle, fused tail
// ---------------------------------------------------------------------------

#define DECAY 0.99f
#define OMD   0.01f
#define EPSC  1e-5f
#define MARGIN 0.008f

constexpr int Dq = 256;
constexpr int Kn = 2048;
constexpr int Nq = 32768;

typedef short bf16x8 __attribute__((ext_vector_type(8)));
typedef float f32x4 __attribute__((ext_vector_type(4)));

__device__ __forceinline__ unsigned short f2bf_rne(float f) {
    unsigned int u = __float_as_uint(f);
    unsigned int r = u + 0x7FFFu + ((u >> 16) & 1u);
    return (unsigned short)(r >> 16);
}
__device__ __forceinline__ float bf2f(unsigned short h) {
    return __uint_as_float(((unsigned int)h) << 16);
}
__device__ __forceinline__ void async_copy16(const void* g, void* l) {
    __builtin_amdgcn_global_load_lds(
        (const __attribute__((address_space(1))) unsigned int*)g,
        (__attribute__((address_space(3))) unsigned int*)l, 16, 0, 0);
}
__device__ __forceinline__ uint4 packbf(const unsigned short* h) {
    uint4 u;
    u.x = (unsigned)h[0] | ((unsigned)h[1] << 16);
    u.y = (unsigned)h[2] | ((unsigned)h[3] << 16);
    u.z = (unsigned)h[4] | ((unsigned)h[5] << 16);
    u.w = (unsigned)h[6] | ((unsigned)h[7] << 16);
    return u;
}

// ---------------- convert: fp32 -> frag-order bf16 hi/lo planes + enorm -----
// One wave per 16-row block; wave writes whole contiguous 1KB granule blocks.
__global__ __launch_bounds__(256) void convert_kernel(
    const float* __restrict__ x, const float* __restrict__ emb,
    unsigned char* __restrict__ xh_g, unsigned char* __restrict__ xl_g,
    unsigned char* __restrict__ eh_g, unsigned char* __restrict__ el_g,
    float* __restrict__ enorm, int* __restrict__ counts,
    float* __restrict__ loss_acc, int* __restrict__ nflag)
{
    int t = threadIdx.x;
    if (blockIdx.x == 0) {
        for (int i = t; i < Kn; i += 256) counts[i] = 0;
        if (t == 0) { loss_acc[0] = 0.f; nflag[0] = 0; }
    }
    int wave = t >> 6, lane = t & 63;
    int g = blockIdx.x * 4 + wave;            // 16-row block id, 0..2175
    bool is_e = (g >= Nq / 16);
    int gg = is_e ? (g - Nq / 16) : g;
    unsigned char* hg = is_e ? eh_g : xh_g;
    unsigned char* lg = is_e ? el_g : xl_g;
    int rl = lane >> 2, qd = lane & 3;
    int row = gg * 16 + rl;
    const float* rp = (is_e ? emb : x) + (size_t)row * Dq;
    float esum = 0.f;
#pragma unroll
    for (int ds = 0; ds < 8; ++ds) {
        float4 v0 = *(const float4*)(rp + ds * 32 + qd * 8);
        float4 v1 = *(const float4*)(rp + ds * 32 + qd * 8 + 4);
        float vv[8] = {v0.x, v0.y, v0.z, v0.w, v1.x, v1.y, v1.z, v1.w};
        unsigned short hh[8], ll[8];
#pragma unroll
        for (int i = 0; i < 8; ++i) {
            hh[i] = f2bf_rne(vv[i]);
            ll[i] = f2bf_rne(vv[i] - bf2f(hh[i]));
        }
        size_t gb = ((size_t)gg * 8 + ds) * 1024 + qd * 256 + rl * 16;
        *(uint4*)(hg + gb) = packbf(hh);
        *(uint4*)(lg + gb) = packbf(ll);
        if (is_e) {
#pragma unroll
            for (int i = 0; i < 8; ++i) esum += vv[i] * vv[i];
        }
    }
    if (is_e) {
        esum += __shfl_xor(esum, 1, 64);
        esum += __shfl_xor(esum, 2, 64);
        if (qd == 0) enorm[row] = esum;
    }
}

// ---------------- argmin: MFMA 3-term, 128q x 1024k per block (split=2) -----
// XCD swizzle: split = bx>>8, qb = bx&255 -> both splits of a qb share an XCD.
__global__ __launch_bounds__(256, 2) void argmin_kernel(
    const unsigned char* __restrict__ xh_g, const unsigned char* __restrict__ xl_g,
    const unsigned char* __restrict__ eh_g, const unsigned char* __restrict__ el_g,
    const float* __restrict__ enorm,
    float* __restrict__ ws_s1, float* __restrict__ ws_s2, int* __restrict__ ws_k)
{
    __shared__ __align__(16) unsigned char lds[69632];
    const int tid = threadIdx.x;
    const int lane = tid & 63, wave = tid >> 6;
    const int wq = wave >> 1, wk = wave & 1;
    const int rl = lane & 15, quad = lane >> 4;
    const int qb = blockIdx.x & 255;
    const int split = blockIdx.x >> 8;

    ((float4*)(lds + 65536))[tid] = ((const float4*)(enorm + split * 1024))[tid];

    float s1[16], s2[16];
    int i1[16];
#pragma unroll
    for (int s = 0; s < 16; ++s) { s1[s] = 3.4e38f; s2[s] = 3.4e38f; i1[s] = 0; }

    const unsigned char* pg = (wave == 0) ? xh_g : (wave == 1) ? xl_g
                              : (wave == 2) ? eh_g : el_g;
    const int rb_x = qb * 8;

    for (int kt = 0; kt < 8; ++kt) {
        f32x4 acc[4][4];
#pragma unroll
        for (int mf = 0; mf < 4; ++mf)
#pragma unroll
            for (int nf = 0; nf < 4; ++nf) acc[mf][nf] = (f32x4){0.f, 0.f, 0.f, 0.f};

        const int rbase = (wave < 2) ? rb_x : (split * 64 + kt * 8);

        for (int ch = 0; ch < 4; ++ch) {
            __syncthreads();
#pragma unroll
            for (int i = 0; i < 16; ++i) {
                int mfb = i >> 1, ds = i & 1;
                size_t goff = ((size_t)(rbase + mfb) * 8 + ch * 2 + ds) * 1024
                              + (size_t)lane * 16;
                async_copy16(pg + goff, lds + wave * 16384 + i * 1024);
            }
            __syncthreads();
#pragma unroll
            for (int ds = 0; ds < 2; ++ds) {
                bf16x8 ah[4], al[4], bh[4], bl[4];
#pragma unroll
                for (int mf = 0; mf < 4; ++mf) {
                    int blk = ((wq * 4 + mf) * 2 + ds) * 1024 + lane * 16;
                    ah[mf] = *(const bf16x8*)(lds + blk);
                    al[mf] = *(const bf16x8*)(lds + 16384 + blk);
                }
#pragma unroll
                for (int nf = 0; nf < 4; ++nf) {
                    int blk = ((wk * 4 + nf) * 2 + ds) * 1024 + lane * 16;
                    bh[nf] = *(const bf16x8*)(lds + 32768 + blk);
                    bl[nf] = *(const bf16x8*)(lds + 49152 + blk);
                }
#pragma unroll
                for (int mf = 0; mf < 4; ++mf)
#pragma unroll
                    for (int nf = 0; nf < 4; ++nf) {
                        acc[mf][nf] = __builtin_amdgcn_mfma_f32_16x16x32_bf16(
                            ah[mf], bh[nf], acc[mf][nf], 0, 0, 0);
                        acc[mf][nf] = __builtin_amdgcn_mfma_f32_16x16x32_bf16(
                            ah[mf], bl[nf], acc[mf][nf], 0, 0, 0);
                        acc[mf][nf] = __builtin_amdgcn_mfma_f32_16x16x32_bf16(
                            al[mf], bh[nf], acc[mf][nf], 0, 0, 0);
                    }
            }
        }
#pragma unroll
        for (int nf = 0; nf < 4; ++nf) {
            float ee = *(const float*)(lds + 65536 +
                         (kt * 128 + wk * 64 + nf * 16 + rl) * 4);
            int code = kt * 4 + nf;
#pragma unroll
            for (int mf = 0; mf < 4; ++mf)
#pragma unroll
                for (int r = 0; r < 4; ++r) {
                    int slot = mf * 4 + r;
                    float sc = fmaf(-2.f, acc[mf][nf][r], ee);
                    float worst = fmaxf(s1[slot], sc);
                    s2[slot] = fminf(s2[slot], worst);
                    bool lt = sc < s1[slot];
                    s1[slot] = lt ? sc : s1[slot];
                    i1[slot] = lt ? code : i1[slot];
                }
        }
    }

    int kf[16];
#pragma unroll
    for (int s = 0; s < 16; ++s)
        kf[s] = split * 1024 + (i1[s] >> 2) * 128 + wk * 64 + (i1[s] & 3) * 16 + rl;
#pragma unroll
    for (int m = 1; m <= 8; m <<= 1) {
#pragma unroll
        for (int s = 0; s < 16; ++s) {
            float os1 = __shfl_xor(s1[s], m, 64);
            float os2 = __shfl_xor(s2[s], m, 64);
            int   ok  = __shfl_xor(kf[s], m, 64);
            float worst = fmaxf(s1[s], os1);
            s2[s] = fminf(fminf(s2[s], os2), worst);
            bool take = (os1 < s1[s]) || (os1 == s1[s] && ok < kf[s]);
            s1[s] = take ? os1 : s1[s];
            kf[s] = take ? ok : kf[s];
        }
    }
    __syncthreads();
    float* rs1 = (float*)lds;
    float* rs2 = (float*)(lds + 1024);
    int*   rk  = (int*)(lds + 2048);
    if (rl == 0) {
#pragma unroll
        for (int s = 0; s < 16; ++s) {
            int ql = wq * 64 + (s >> 2) * 16 + quad * 4 + (s & 3);
            rs1[ql * 2 + wk] = s1[s];
            rs2[ql * 2 + wk] = s2[s];
            rk[ql * 2 + wk]  = kf[s];
        }
    }
    __syncthreads();
    if (tid < 128) {
        float a1 = rs1[tid * 2], b1 = rs1[tid * 2 + 1];
        float a2 = rs2[tid * 2], b2 = rs2[tid * 2 + 1];
        int ka = rk[tid * 2], kb = rk[tid * 2 + 1];
        bool take = (b1 < a1) || (b1 == a1 && kb < ka);
        float fs1 = take ? b1 : a1;
        int   fk  = take ? kb : ka;
        float fs2 = fminf(fminf(a2, b2), fmaxf(a1, b1));
        int q = qb * 128 + tid;
        ws_s1[split * Nq + q] = fs1;
        ws_s2[split * Nq + q] = fs2;
        ws_k[split * Nq + q]  = fk;
    }
}

// ---------------- pick: merge splits, idx+idx_f, flag, LDS histogram --------
__global__ __launch_bounds__(256) void pick_kernel(
    const float* __restrict__ ws_s1, const float* __restrict__ ws_s2,
    const int* __restrict__ ws_k, int* __restrict__ idx,
    float* __restrict__ idx_f_out,
    int* __restrict__ nflag, int* __restrict__ flaglist,
    int* __restrict__ counts)
{
    __shared__ int h[Kn];
    int t = threadIdx.x;
#pragma unroll
    for (int i = 0; i < 8; ++i) h[t + i * 256] = 0;
    __syncthreads();
    int q = blockIdx.x * 256 + t;
    float a1 = ws_s1[q], b1 = ws_s1[Nq + q];
    float a2 = ws_s2[q], b2 = ws_s2[Nq + q];
    int ka = ws_k[q], kb = ws_k[Nq + q];
    bool take = (b1 < a1) || (b1 == a1 && kb < ka);
    float s1 = take ? b1 : a1;
    int k = take ? kb : ka;
    float s2 = fminf(fminf(a2, b2), fmaxf(a1, b1));
    idx[q] = k;
    idx_f_out[q] = (float)k;
    atomicAdd(&h[k], 1);
    if (s2 - s1 < MARGIN) {
        int p = atomicAdd(nflag, 1);
        flaglist[p] = q;
    }
    __syncthreads();
#pragma unroll
    for (int i = 0; i < 8; ++i) {
        int c = h[t + i * 256];
        if (c) atomicAdd(&counts[t + i * 256], c);
    }
}

// ---------------- rescue: exact fp32 argmin for flagged queries -------------
__global__ __launch_bounds__(256) void rescue_kernel(
    const float* __restrict__ x, const float* __restrict__ emb,
    const float* __restrict__ enorm, const int* __restrict__ flaglist,
    const int* __restrict__ nflag, int* __restrict__ idx,
    float* __restrict__ idx_f_out, int* __restrict__ counts)
{
    __shared__ float xs[256];
    __shared__ float bsc[256];
    __shared__ int bix[256];
    int nf = nflag[0];
    int t = threadIdx.x;
    for (int it = blockIdx.x; it < nf; it += gridDim.x) {
        __syncthreads();
        int q = flaglist[it];
        xs[t] = x[(size_t)q * Dq + t];
        __syncthreads();
        float best = 3.4e38f;
        int bk = 0;
        for (int j = 0; j < 8; ++j) {
            int k = j * 256 + t;
            const float4* e4 = (const float4*)(emb + (size_t)k * Dq);
            const float4* x4 = (const float4*)xs;
            float d = 0.f;
#pragma unroll 8
            for (int c = 0; c < 64; ++c) {
                float4 e = e4[c], xv = x4[c];
                d = fmaf(e.x, xv.x, d); d = fmaf(e.y, xv.y, d);
                d = fmaf(e.z, xv.z, d); d = fmaf(e.w, xv.w, d);
            }
            float sc = enorm[k] - 2.f * d;
            if (sc < best || (sc == best && k < bk)) { best = sc; bk = k; }
        }
        bsc[t] = best; bix[t] = bk;
        __syncthreads();
        for (int o = 128; o > 0; o >>= 1) {
            if (t < o) {
                float so = bsc[t + o]; int io = bix[t + o];
                if (so < bsc[t] || (so == bsc[t] && io < bix[t])) {
                    bsc[t] = so; bix[t] = io;
                }
            }
            __syncthreads();
        }
        if (t == 0) {
            int newk = bix[0], oldk = idx[q];
            if (newk != oldk) {
                idx[q] = newk;
                idx_f_out[q] = (float)newk;
                atomicSub(&counts[oldk], 1);
                atomicAdd(&counts[newk], 1);
            }
        }
    }
}

// ---------------- scan: smoothed counts -------------------------------------
__global__ __launch_bounds__(256) void scan_kernel(
    const int* __restrict__ counts, const float* __restrict__ ema_count,
    float* __restrict__ cnew, float* __restrict__ out_count)
{
    __shared__ int   si[256];
    __shared__ float sf[256];
    int t = threadIdx.x;
    int c[8];
    int run = 0;
    float se = 0.f;
#pragma unroll
    for (int i = 0; i < 8; ++i) {
        c[i] = counts[t * 8 + i];
        run += c[i];
        se += ema_count[t * 8 + i];
    }
    si[t] = run;
    sf[t] = se;
    __syncthreads();
    for (int off = 128; off > 0; off >>= 1) {
        if (t < off) { si[t] += si[t + off]; sf[t] += sf[t + off]; }
        __syncthreads();
    }
    float total = DECAY * sf[0] + OMD * (float)si[0];
    float denom = total + 2048.0f * EPSC;
#pragma unroll
    for (int i = 0; i < 8; ++i) {
        int k = t * 8 + i;
        float ck = DECAY * ema_count[k] + OMD * (float)c[i];
        float v = (ck + EPSC) / denom * total;
        cnew[k] = v;
        out_count[k] = v;
    }
}

// ---------------- apply: gather z_q + loss + atomic accum (fused) -----------
__global__ __launch_bounds__(256) void apply_kernel(
    const float* __restrict__ x, const float* __restrict__ emb,
    const int* __restrict__ idx, float* __restrict__ zq_out,
    float* __restrict__ accum, float* __restrict__ loss_acc)
{
    __shared__ float lpart[4];
    int wave = threadIdx.x >> 6, lane = threadIdx.x & 63;
    int n = blockIdx.x * 4 + wave;
    int k = idx[n];
    float4 xv = *(const float4*)(x + (size_t)n * Dq + lane * 4);
    float4 ev = *(const float4*)(emb + (size_t)k * Dq + lane * 4);
    *(float4*)(zq_out + (size_t)n * Dq + lane * 4) = ev;
    float* a = accum + (size_t)k * Dq + lane * 4;
    atomicAdd(a + 0, xv.x);
    atomicAdd(a + 1, xv.y);
    atomicAdd(a + 2, xv.z);
    atomicAdd(a + 3, xv.w);
    float d0 = xv.x - ev.x, d1 = xv.y - ev.y;
    float d2 = xv.z - ev.z, d3 = xv.w - ev.w;
    float l = d0 * d0 + d1 * d1 + d2 * d2 + d3 * d3;
#pragma unroll
    for (int o = 32; o > 0; o >>= 1) l += __shfl_down(l, o, 64);
    if (lane == 0) lpart[wave] = l;
    __syncthreads();
    if (threadIdx.x == 0)
        atomicAdd(loss_acc, lpart[0] + lpart[1] + lpart[2] + lpart[3]);
}

// ---------------- weight_final: EMA + divide (float2: accum is 8B-aligned) --
__global__ __launch_bounds__(256) void weight_final_kernel(
    const float* __restrict__ accum, const float* __restrict__ ema_weight,
    const float* __restrict__ cnew,
    float* __restrict__ out_embed, float* __restrict__ out_weight)
{
    int gi = blockIdx.x * 256 + threadIdx.x;   // float2 index, Kn*Dq/2 total
    int k = gi >> 7;                           // 128 float2 per row
    float2 a = ((const float2*)accum)[gi];
    float2 ew = ((const float2*)ema_weight)[gi];
    float inv = 1.f / cnew[k];
    float2 w;
    w.x = DECAY * ew.x + OMD * a.x;
    w.y = DECAY * ew.y + OMD * a.y;
    ((float2*)out_weight)[gi] = w;
    float2 e;
    e.x = w.x * inv; e.y = w.y * inv;
    ((float2*)out_embed)[gi] = e;
}

// ---------------- loss_final ------------------------------------------------
__global__ void loss_final_kernel(const float* __restrict__ loss_acc,
                                  float* __restrict__ out_cb,
                                  float* __restrict__ out_cm) {
    float v = loss_acc[0] / (float)((size_t)Nq * Dq);
    out_cb[0] = v;
    out_cm[0] = v;
}

// ---------------------------------------------------------------------------
extern "C" void kernel_launch(void* const* d_in, const int* in_sizes, int n_in,
                              void* d_out, int out_size, void* d_ws, size_t ws_size,
                              hipStream_t stream) {
    const float* z_e        = (const float*)d_in[0];
    const float* emb        = (const float*)d_in[1];
    const float* ema_count  = (const float*)d_in[2];
    const float* ema_weight = (const float*)d_in[3];

    float* out_zq     = (float*)d_out;
    float* out_idx    = out_zq + (size_t)Nq * Dq;            // elt 8388608
    float* out_cb     = out_idx + Nq;
    float* out_cm     = out_cb + 1;
    float* out_embed  = out_cm + 1;                           // elt 8421378
    float* out_count  = out_embed + (size_t)Kn * Dq;
    float* out_weight = out_count + Kn;

    // scratch planes live in d_out regions written later:
    unsigned char* xh_g = (unsigned char*)d_out;              // 16 MB (z_q area)
    unsigned char* xl_g = xh_g + 16777216;                    // 16 MB
    size_t eh_off = (((size_t)8421378 * 4) + 15) & ~(size_t)15;
    unsigned char* eh_g = (unsigned char*)d_out + eh_off;     // 1 MB (embed area)
    unsigned char* el_g = eh_g + 1048576;                     // 1 MB
    // accum = out_embed region (2 MB), dead for planes after argmin
    float* accum = out_embed;

    char* ws = (char*)d_ws;
    float* enorm    = (float*)(ws + 0);
    int*   counts   = (int*)(ws + 8192);
    float* cnew     = (float*)(ws + 16384);
    float* loss_acc = (float*)(ws + 24576);
    int*   nflag    = (int*)(ws + 24580);
    int*   idx      = (int*)(ws + 32768);       // 32768 i
    int*   flaglist = (int*)(ws + 163840);      // 32768 i
    float* ws_s1    = (float*)(ws + 294912);    // 2*32768 f
    float* ws_s2    = (float*)(ws + 557056);    // 2*32768 f
    int*   ws_k     = (int*)(ws + 819200);      // 2*32768 i

    convert_kernel<<<544, 256, 0, stream>>>(z_e, emb, xh_g, xl_g, eh_g, el_g,
                                            enorm, counts, loss_acc, nflag);
    argmin_kernel<<<512, 256, 0, stream>>>(xh_g, xl_g, eh_g, el_g, enorm,
                                           ws_s1, ws_s2, ws_k);
    hipMemsetAsync(accum, 0, (size_t)Kn * Dq * sizeof(float), stream);
    pick_kernel<<<Nq / 256, 256, 0, stream>>>(ws_s1, ws_s2, ws_k, idx, out_idx,
                                              nflag, flaglist, counts);
    rescue_kernel<<<128, 256, 0, stream>>>(z_e, emb, enorm, flaglist, nflag,
                                           idx, out_idx, counts);
    scan_kernel<<<1, 256, 0, stream>>>(counts, ema_count, cnew, out_count);
    apply_kernel<<<Nq / 4, 256, 0, stream>>>(z_e, emb, idx, out_zq, accum, loss_acc);
    weight_final_kernel<<<Kn * Dq / 512, 256, 0, stream>>>(accum, ema_weight, cnew,
                                                           out_embed, out_weight);
    loss_final_kernel<<<1, 1, 0, stream>>>(loss_acc, out_cb, out_cm);
}